// Round 9
// baseline (14.986 us; speedup 1.0000x reference)
//
#include <hip/hip_runtime.h>
#include <math.h>

#define BATCH 16
#define NPTS 17
#define MPTS 4096
#define NPAIR 136                    // 17*16/2 pairs (i>j)
#define NPAIRS_TOTAL (BATCH * NPAIR) // 2176
#define NKEY (BATCH * NPTS)          // 272 keypoints
#define NBLK (NPAIRS_TOTAL + NKEY)   // 2176 pair blocks + 272 keypoint blocks
#define MAXDIS 1e-3f
#define EPS_ABS 1e-5f

// d2(t) = A + t*B + t^2*E with A=||p_j-g||^2, B=2e.(p_j-g), E=||e||^2, e=p_i-p_j.
// t=0 min  = min_g||p_j-g||^2            -> per-KEYPOINT j (hoisted out of pair loop)
// t=1 min  = min_g||p_i-g||^2 - E        -> per-KEYPOINT i (hoisted)
// Pair blocks track only the t={.25,.5,.75} shifted mins ms_c = min_g(A + t_c*B);
// keypoint blocks compute pmin[k] = min_g||p_k-g||^2. Kernel 2 assembles
// cdis = (pmin[j] + (m1+m2+m3) + pmin[i]) / 5 per pair (min is rounding-free,
// so pmin/ms are bit-exact under any scan split).
__global__ __launch_bounds__(256) void pair_kernel(const float* __restrict__ recon,
                                                   const float* __restrict__ gt,
                                                   float4* __restrict__ slots,
                                                   float* __restrict__ pmin) {
    const int blk = blockIdx.x;
    const int wave = threadIdx.x >> 6;
    const int lane = threadIdx.x & 63;

    if (blk >= NPAIRS_TOTAL) {
        // ---- keypoint block: pmin[k] = min_g ||p_k - g||^2, 4-wave split scan
        const int k = blk - NPAIRS_TOTAL;       // keypoint id in [0, 272)
        const int b = k / NPTS;
        const int pt = k - b * NPTS;
        const float px = recon[b * NPTS * 2 + 2 * pt];
        const float py = recon[b * NPTS * 2 + 2 * pt + 1];

        float mn = 1e30f;
        const float4* g4 = (const float4*)(gt + (size_t)b * MPTS * 2);
        #pragma unroll
        for (int it = 0; it < 8; ++it) {
            const float4 g = g4[threadIdx.x + (it << 8)];
            const float dxa = px - g.x, dya = py - g.y;
            const float dxb = px - g.z, dyb = py - g.w;
            const float Aa = fmaf(dxa, dxa, dya * dya);
            const float Ab = fmaf(dxb, dxb, dyb * dyb);
            mn = fminf(mn, fminf(Aa, Ab));
        }
        #pragma unroll
        for (int off = 32; off > 0; off >>= 1)
            mn = fminf(mn, __shfl_xor(mn, off, 64));

        __shared__ float kpart[4];
        if (lane == 0) kpart[wave] = mn;
        __syncthreads();
        if (threadIdx.x == 0)
            pmin[k] = fminf(fminf(kpart[0], kpart[1]), fminf(kpart[2], kpart[3]));
        return;
    }

    // ---- pair block: 4 waves each scan a quarter of the 4096 gt points
    const int b = blk / NPAIR;
    const int p = blk - b * NPAIR;
    // decode p -> (i, j), p = i*(i-1)/2 + j, j < i  (block-uniform scalar loop)
    int i = 1;
    while ((i * (i + 1)) / 2 <= p) ++i;
    const int j = p - (i * (i - 1)) / 2;

    const float* rp = recon + b * NPTS * 2;
    const float pix = rp[2 * i], piy = rp[2 * i + 1];
    const float pjx = rp[2 * j], pjy = rp[2 * j + 1];

    const float ex = pix - pjx, ey = piy - pjy;
    const float e2x = 2.0f * ex, e2y = 2.0f * ey;
    const float E = ex * ex + ey * ey;

    float ms1 = 1e30f, ms2 = 1e30f, ms3 = 1e30f;

    const float4* g4 = (const float4*)(gt + (size_t)b * MPTS * 2);
    #pragma unroll
    for (int it = 0; it < 8; ++it) {
        const float4 g = g4[threadIdx.x + (it << 8)];
        const float dxa = pjx - g.x, dya = pjy - g.y;
        const float Aa = fmaf(dxa, dxa, dya * dya);
        const float Ba = fmaf(e2x, dxa, e2y * dya);
        const float dxb = pjx - g.z, dyb = pjy - g.w;
        const float Ab = fmaf(dxb, dxb, dyb * dyb);
        const float Bb = fmaf(e2x, dxb, e2y * dyb);

        ms1 = fminf(ms1, fminf(fmaf(0.25f, Ba, Aa), fmaf(0.25f, Bb, Ab)));
        ms2 = fminf(ms2, fminf(fmaf(0.50f, Ba, Aa), fmaf(0.50f, Bb, Ab)));
        ms3 = fminf(ms3, fminf(fmaf(0.75f, Ba, Aa), fmaf(0.75f, Bb, Ab)));
    }

    #pragma unroll
    for (int off = 32; off > 0; off >>= 1) {
        ms1 = fminf(ms1, __shfl_xor(ms1, off, 64));
        ms2 = fminf(ms2, __shfl_xor(ms2, off, 64));
        ms3 = fminf(ms3, __shfl_xor(ms3, off, 64));
    }

    __shared__ float part[4][3];
    if (lane == 0) {
        part[wave][0] = ms1;
        part[wave][1] = ms2;
        part[wave][2] = ms3;
    }
    __syncthreads();

    if (threadIdx.x == 0) {
        const float r1 = fminf(fminf(part[0][0], part[1][0]), fminf(part[2][0], part[3][0]));
        const float r2 = fminf(fminf(part[0][1], part[1][1]), fminf(part[2][1], part[3][1]));
        const float r3 = fminf(fminf(part[0][2], part[1][2]), fminf(part[2][2], part[3][2]));
        // un-shift: m_c = ms_c + t_c^2 * E
        const float m1 = fmaf(0.0625f, E, r1);
        const float m2 = fmaf(0.25f, E, r2);
        const float m3 = fmaf(0.5625f, E, r3);
        const float s123 = (m1 + m2) + m3;

        // cos term (unconditional; kernel 2 applies the threshold)
        const float u0x = rp[0], u0y = rp[1];
        const float uix = u0x - pix, uiy = u0y - piy;
        const float ujx = u0x - pjx, ujy = u0y - pjy;
        const float dot = fabsf(uix * ujx + uiy * ujy);
        const float ai = sqrtf((uix * uix + EPS_ABS) + (uiy * uiy + EPS_ABS));
        const float aj = sqrtf((ujx * ujx + EPS_ABS) + (ujy * ujy + EPS_ABS));
        const float cosv = dot / (ai * aj);

        float4 s;
        s.x = cosv;
        s.y = s123;
        s.z = __int_as_float(b * NPTS + i);
        s.w = __int_as_float(b * NPTS + j);
        slots[blk] = s;
    }
}

// Kernel 2: ONE WAVE. 64 lanes stride the 2176 pair slots (34 exact iters,
// fixed order), assemble cdis from the hoisted keypoint mins, threshold,
// butterfly-sum, lane 0 writes the scalar.
__global__ __launch_bounds__(64) void reduce_kernel(const float4* __restrict__ slots,
                                                    const float* __restrict__ pmin,
                                                    float* __restrict__ out) {
    const int lane = threadIdx.x;
    float c = 0.0f, n = 0.0f;
    #pragma unroll
    for (int m = 0; m < NPAIRS_TOTAL / 64; ++m) {
        const float4 s = slots[lane + 64 * m];
        const float pmi = pmin[__float_as_int(s.z)];
        const float pmj = pmin[__float_as_int(s.w)];
        const float cdis = ((pmj + s.y) + pmi) / 5.0f;
        if (cdis < MAXDIS) {
            c += s.x;
            n += 1.0f;
        }
    }
    #pragma unroll
    for (int off = 32; off > 0; off >>= 1) {
        c += __shfl_xor(c, off, 64);
        n += __shfl_xor(n, off, 64);
    }
    if (lane == 0) out[0] = c / (1.0f + n);
}

extern "C" void kernel_launch(void* const* d_in, const int* in_sizes, int n_in,
                              void* d_out, int out_size, void* d_ws, size_t ws_size,
                              hipStream_t stream) {
    const float* recon = (const float*)d_in[0]; // [16,17,2] f32
    const float* gt = (const float*)d_in[1];    // [16,4096,2] f32
    float* out = (float*)d_out;                 // scalar f32
    float4* slots = (float4*)d_ws;               // 2176 float4 pair slots
    float* pmin = (float*)((char*)d_ws + (size_t)NPAIRS_TOTAL * 16); // 272 floats

    pair_kernel<<<NBLK, 256, 0, stream>>>(recon, gt, slots, pmin);
    reduce_kernel<<<1, 64, 0, stream>>>(slots, pmin, out);
}

// Round 10
// 13.311 us; speedup vs baseline: 1.1259x; 1.1259x over previous
//
#include <hip/hip_runtime.h>
#include <math.h>

#define BATCH 16
#define NPTS 17
#define MPTS 4096
#define NPAIR 136                    // 17*16/2 pairs (i>j)
#define NPAIRS_TOTAL (BATCH * NPAIR) // 2176
#define CNT 5
#define MAXDIS 1e-3f
#define EPS_ABS 1e-5f

// R8 structure (measured best: 13.15 us). One block per pair (2176 blocks,
// 256 threads). The 4 waves each scan a quarter of the 4096 gt points
// (8 fully-unrolled float4 iters/lane), tracking the 5 shifted mins
// ms_c = min_g(A + t_c*B) of the quadratic form
//   d2(t) = A + t*B + t^2*E,  A=||p_j-g||^2, B=2e.(p_j-g), E=||e||^2.
// Butterfly per wave -> 4x5 LDS min-combine -> thread 0 un-shifts (+t_c^2*E),
// means, thresholds, computes the cos term, writes one float2 slot.
__global__ __launch_bounds__(256) void pair_kernel(const float* __restrict__ recon,
                                                   const float* __restrict__ gt,
                                                   float2* __restrict__ slots) {
    const int blk = blockIdx.x;      // pair id in [0, 2176)
    const int wave = threadIdx.x >> 6;
    const int lane = threadIdx.x & 63;
    const int b = blk / NPAIR;
    const int p = blk - b * NPAIR;
    // decode p -> (i, j), p = i*(i-1)/2 + j, j < i  (block-uniform scalar loop)
    int i = 1;
    while ((i * (i + 1)) / 2 <= p) ++i;
    const int j = p - (i * (i - 1)) / 2;

    const float* rp = recon + b * NPTS * 2;
    const float pix = rp[2 * i], piy = rp[2 * i + 1];
    const float pjx = rp[2 * j], pjy = rp[2 * j + 1];

    const float ex = pix - pjx, ey = piy - pjy;
    const float e2x = 2.0f * ex, e2y = 2.0f * ey;
    const float E = ex * ex + ey * ey;

    float ms0 = 1e30f, ms1 = 1e30f, ms2 = 1e30f, ms3 = 1e30f, ms4 = 1e30f;

    const float4* g4 = (const float4*)(gt + (size_t)b * MPTS * 2);
    #pragma unroll
    for (int it = 0; it < 8; ++it) {
        const float4 g = g4[threadIdx.x + (it << 8)];
        // point a
        const float dxa = pjx - g.x, dya = pjy - g.y;
        const float Aa = fmaf(dxa, dxa, dya * dya);
        const float Ba = fmaf(e2x, dxa, e2y * dya);
        // point b
        const float dxb = pjx - g.z, dyb = pjy - g.w;
        const float Ab = fmaf(dxb, dxb, dyb * dyb);
        const float Bb = fmaf(e2x, dxb, e2y * dyb);

        ms0 = fminf(ms0, fminf(Aa, Ab));
        ms1 = fminf(ms1, fminf(fmaf(0.25f, Ba, Aa), fmaf(0.25f, Bb, Ab)));
        ms2 = fminf(ms2, fminf(fmaf(0.50f, Ba, Aa), fmaf(0.50f, Bb, Ab)));
        ms3 = fminf(ms3, fminf(fmaf(0.75f, Ba, Aa), fmaf(0.75f, Bb, Ab)));
        ms4 = fminf(ms4, fminf(Aa + Ba, Ab + Bb));
    }

    // in-wave butterfly min reduce
    #pragma unroll
    for (int off = 32; off > 0; off >>= 1) {
        ms0 = fminf(ms0, __shfl_xor(ms0, off, 64));
        ms1 = fminf(ms1, __shfl_xor(ms1, off, 64));
        ms2 = fminf(ms2, __shfl_xor(ms2, off, 64));
        ms3 = fminf(ms3, __shfl_xor(ms3, off, 64));
        ms4 = fminf(ms4, __shfl_xor(ms4, off, 64));
    }

    __shared__ float part[4][CNT];
    if (lane == 0) {
        part[wave][0] = ms0;
        part[wave][1] = ms1;
        part[wave][2] = ms2;
        part[wave][3] = ms3;
        part[wave][4] = ms4;
    }
    __syncthreads();

    if (threadIdx.x == 0) {
        float m[CNT];
        #pragma unroll
        for (int c = 0; c < CNT; ++c)
            m[c] = fminf(fminf(part[0][c], part[1][c]),
                         fminf(part[2][c], part[3][c]));
        // un-shift: mn[c] = ms[c] + t_c^2 * E; mean over the 5 samples
        const float m0 = m[0];
        const float m1 = fmaf(0.0625f, E, m[1]);
        const float m2 = fmaf(0.25f, E, m[2]);
        const float m3 = fmaf(0.5625f, E, m[3]);
        const float m4 = m[4] + E;
        const float cdis = ((((m0 + m1) + m2) + m3) + m4) / 5.0f;

        float cosv = 0.0f, cntv = 0.0f;
        if (cdis < MAXDIS) {
            const float u0x = rp[0], u0y = rp[1];
            const float uix = u0x - pix, uiy = u0y - piy;
            const float ujx = u0x - pjx, ujy = u0y - pjy;
            const float dot = fabsf(uix * ujx + uiy * ujy);
            const float ai = sqrtf((uix * uix + EPS_ABS) + (uiy * uiy + EPS_ABS));
            const float aj = sqrtf((ujx * ujx + EPS_ABS) + (ujy * ujy + EPS_ABS));
            cosv = dot / (ai * aj);
            cntv = 1.0f;
        }
        slots[blk] = make_float2(cosv, cntv);
    }
}

// Kernel 2: ONE WAVE. 64 lanes stride the 2176 pair slots (34 exact iters,
// fixed order), butterfly shuffle sum, lane 0 writes the scalar.
__global__ __launch_bounds__(64) void reduce_kernel(const float2* __restrict__ slots,
                                                    float* __restrict__ out) {
    const int lane = threadIdx.x;
    float c = 0.0f, n = 0.0f;
    #pragma unroll
    for (int m = 0; m < NPAIRS_TOTAL / 64; ++m) {
        const float2 w = slots[lane + 64 * m];
        c += w.x;
        n += w.y;
    }
    #pragma unroll
    for (int off = 32; off > 0; off >>= 1) {
        c += __shfl_xor(c, off, 64);
        n += __shfl_xor(n, off, 64);
    }
    if (lane == 0) out[0] = c / (1.0f + n);
}

extern "C" void kernel_launch(void* const* d_in, const int* in_sizes, int n_in,
                              void* d_out, int out_size, void* d_ws, size_t ws_size,
                              hipStream_t stream) {
    const float* recon = (const float*)d_in[0]; // [16,17,2] f32
    const float* gt = (const float*)d_in[1];    // [16,4096,2] f32
    float* out = (float*)d_out;                 // scalar f32
    float2* slots = (float2*)d_ws;              // 2176 float2 pair slots

    pair_kernel<<<NPAIRS_TOTAL, 256, 0, stream>>>(recon, gt, slots);
    reduce_kernel<<<1, 64, 0, stream>>>(slots, out);
}